// Round 1
// baseline (1441.356 us; speedup 1.0000x reference)
//
#include <hip/hip_runtime.h>
#include <math.h>

#define N_CH 256
#define T_IN 100000
#define L1O 20000
#define L2O 4000
#define L3O 800
#define C1 8
#define C2 16
#define C3 32

// ---------- fused conv tile geometry ----------
#define TILE3 25      // conv3 outputs per block
#define NY2   125     // conv2 positions needed
#define NY1   627     // conv1 positions needed
#define ND    3141    // data samples needed

__device__ __forceinline__ float sigm(float x) {
    x = fminf(fmaxf(x, -30.0f), 30.0f);
    return 1.0f / (1.0f + __expf(-x));
}
__device__ __forceinline__ float tanhfast(float x) {
    x = fminf(fmaxf(x, -15.0f), 15.0f);
    float e = __expf(-2.0f * x);
    return (1.0f - e) / (1.0f + e);
}

// ================= K1: fused conv1+conv2+conv3 =================
// grid (32 tiles, 256 channels), 256 threads
__global__ __launch_bounds__(256) void k_conv(
    const float* __restrict__ data,
    const float* __restrict__ w1, const float* __restrict__ b1,
    const float* __restrict__ w2, const float* __restrict__ b2,
    const float* __restrict__ w3, const float* __restrict__ b3,
    float* __restrict__ x3)
{
    __shared__ float sd[ND];
    __shared__ float sy1[NY1][C1];
    __shared__ float sy2[NY2][C2];
    __shared__ float sw1[C1 * 11], sb1[C1];
    __shared__ float sw2[C2 * C1 * 7], sb2[C2];
    __shared__ float sw3[C3 * C2 * 5], sb3[C3];

    const int tid = threadIdx.x;
    const int tb  = blockIdx.x;   // tile
    const int ch  = blockIdx.y;   // channel
    const int t0    = tb * TILE3;
    const int dbase = 3125 * tb - 70;
    const int ubase = 625 * tb - 13;
    const int sbase = 125 * tb - 2;

    for (int e = tid; e < C1 * 11;    e += 256) sw1[e] = w1[e];
    for (int e = tid; e < C1;         e += 256) sb1[e] = b1[e];
    for (int e = tid; e < C2 * C1 * 7; e += 256) sw2[e] = w2[e];
    for (int e = tid; e < C2;         e += 256) sb2[e] = b2[e];
    for (int e = tid; e < C3 * C2 * 5; e += 256) sw3[e] = w3[e];
    for (int e = tid; e < C3;         e += 256) sb3[e] = b3[e];

    const float* dch = data + (size_t)ch * T_IN;
    for (int e = tid; e < ND; e += 256) {
        int g = dbase + e;
        sd[e] = (g >= 0 && g < T_IN) ? dch[g] : 0.0f;
    }
    __syncthreads();

    // conv1 (stride 5, k=11, pad 5)
    for (int e = tid; e < NY1 * C1; e += 256) {
        int u = e >> 3, c = e & 7;
        int ug = ubase + u;
        float acc = sb1[c];
        #pragma unroll
        for (int k = 0; k < 11; ++k) acc += sw1[c * 11 + k] * sd[5 * u + k];
        acc = fmaxf(acc, 0.0f);
        sy1[u][c] = (ug >= 0 && ug < L1O) ? acc : 0.0f;
    }
    __syncthreads();

    // conv2 (stride 5, k=7, pad 3)
    for (int e = tid; e < NY2 * C2; e += 256) {
        int s = e >> 4, c = e & 15;
        int sg = sbase + s;
        float acc = sb2[c];
        #pragma unroll
        for (int ci = 0; ci < C1; ++ci)
            #pragma unroll
            for (int k = 0; k < 7; ++k)
                acc += sw2[(c * C1 + ci) * 7 + k] * sy1[5 * s + k][ci];
        acc = fmaxf(acc, 0.0f);
        sy2[s][c] = (sg >= 0 && sg < L2O) ? acc : 0.0f;
    }
    __syncthreads();

    // conv3 (stride 5, k=5, pad 2) -> x3[ch][t][o]
    for (int e = tid; e < TILE3 * C3; e += 256) {
        int tl = e >> 5, o = e & 31;
        float acc = sb3[o];
        #pragma unroll
        for (int ci = 0; ci < C2; ++ci)
            #pragma unroll
            for (int k = 0; k < 5; ++k)
                acc += sw3[(o * C2 + ci) * 5 + k] * sy2[5 * tl + k][ci];
        acc = fmaxf(acc, 0.0f);
        x3[((size_t)ch * L3O + (t0 + tl)) * C3 + o] = acc;
    }
}

// ================= K2: GRU recurrence, 1 wave per (ch, dir) =================
#define CHUNK 100
__global__ __launch_bounds__(64) void k_gru(
    const float* __restrict__ x3,
    const float* __restrict__ wih_f, const float* __restrict__ whh_f,
    const float* __restrict__ bih_f, const float* __restrict__ bhh_f,
    const float* __restrict__ wih_b, const float* __restrict__ whh_b,
    const float* __restrict__ bih_b, const float* __restrict__ bhh_b,
    float* __restrict__ hN)
{
    const int lane = threadIdx.x;
    const int ch   = blockIdx.x;
    const int dir  = blockIdx.y;
    const float* wih = dir ? wih_b : wih_f;
    const float* whh = dir ? whh_b : whh_f;
    const float* bih = dir ? bih_b : bih_f;
    const float* bhh = dir ? bhh_b : bhh_f;

    __shared__ __align__(16) float sh[64];
    __shared__ __align__(16) float sx[CHUNK * 32];

    // per-lane weight rows in registers: rows lane, 64+lane, 128+lane
    float4 wir[8], wiz[8], win[8];
    const float4* wih4 = (const float4*)wih;
    #pragma unroll
    for (int k = 0; k < 8; ++k) {
        wir[k] = wih4[(0   + lane) * 8 + k];
        wiz[k] = wih4[(64  + lane) * 8 + k];
        win[k] = wih4[(128 + lane) * 8 + k];
    }
    float4 whr[16], whz[16], whn[16];
    const float4* whh4 = (const float4*)whh;
    #pragma unroll
    for (int j = 0; j < 16; ++j) {
        whr[j] = whh4[(0   + lane) * 16 + j];
        whz[j] = whh4[(64  + lane) * 16 + j];
        whn[j] = whh4[(128 + lane) * 16 + j];
    }
    const float bir = bih[lane], biz = bih[64 + lane], bin_ = bih[128 + lane];
    const float bhr = bhh[lane], bhz = bhh[64 + lane], bhn  = bhh[128 + lane];

    float h = 0.0f;
    sh[lane] = 0.0f;
    __syncthreads();

    const float* xch = x3 + (size_t)ch * L3O * 32;
    for (int c0 = 0; c0 < L3O; c0 += CHUNK) {
        // stage x chunk in step order
        for (int e = lane; e < CHUNK * 32; e += 64) {
            int tt = e >> 5, k = e & 31;
            int sidx = c0 + tt;
            int t = dir ? (L3O - 1 - sidx) : sidx;
            sx[e] = xch[t * 32 + k];
        }
        __syncthreads();
        for (int tl = 0; tl < CHUNK; ++tl) {
            const float4* xv4 = (const float4*)(sx + tl * 32);
            float gr = 0.f, gz = 0.f, gn = 0.f;
            #pragma unroll
            for (int k = 0; k < 8; ++k) {
                float4 x4 = xv4[k];
                gr += wir[k].x * x4.x + wir[k].y * x4.y + wir[k].z * x4.z + wir[k].w * x4.w;
                gz += wiz[k].x * x4.x + wiz[k].y * x4.y + wiz[k].z * x4.z + wiz[k].w * x4.w;
                gn += win[k].x * x4.x + win[k].y * x4.y + win[k].z * x4.z + win[k].w * x4.w;
            }
            float hr = 0.f, hz = 0.f, hn = 0.f;
            const float4* sh4 = (const float4*)sh;
            #pragma unroll
            for (int j = 0; j < 16; ++j) {
                float4 h4 = sh4[j];
                hr += whr[j].x * h4.x + whr[j].y * h4.y + whr[j].z * h4.z + whr[j].w * h4.w;
                hz += whz[j].x * h4.x + whz[j].y * h4.y + whz[j].z * h4.z + whz[j].w * h4.w;
                hn += whn[j].x * h4.x + whn[j].y * h4.y + whn[j].z * h4.z + whn[j].w * h4.w;
            }
            float r = sigm(gr + bir + hr + bhr);
            float z = sigm(gz + biz + hz + bhz);
            float n = tanhfast(gn + bin_ + r * (hn + bhn));
            h = (1.0f - z) * n + z * h;
            __syncthreads();
            sh[lane] = h;
            __syncthreads();
        }
    }
    hN[ch * 128 + dir * 64 + lane] = h;
}

// ================= K3a: row normalize + hw1 = h_n @ gcn1_w.T =================
__global__ __launch_bounds__(128) void k_norm(
    const float* __restrict__ hN, const float* __restrict__ gcn1_w,
    float* __restrict__ Xn, float* __restrict__ XnT, float* __restrict__ hw1)
{
    const int i = blockIdx.x, tid = threadIdx.x;
    __shared__ float red[128];
    __shared__ float row[128];
    float v = hN[i * 128 + tid];
    row[tid] = v;
    red[tid] = v;
    __syncthreads();
    for (int s = 64; s > 0; s >>= 1) { if (tid < s) red[tid] += red[tid + s]; __syncthreads(); }
    float mean = red[0] / 128.0f;
    __syncthreads();
    float d = v - mean;
    red[tid] = d * d;
    __syncthreads();
    for (int s = 64; s > 0; s >>= 1) { if (tid < s) red[tid] += red[tid + s]; __syncthreads(); }
    float sd = sqrtf(red[0] / 127.0f);
    float xn = d / (sd + 1e-6f);
    Xn[i * 128 + tid] = xn;
    XnT[tid * 256 + i] = xn;
    if (tid < 32) {
        float acc = 0.f;
        for (int k = 0; k < 128; ++k) acc += row[k] * gcn1_w[tid * 128 + k];
        hw1[i * 32 + tid] = acc;
    }
}

// ================= K3b: corr row -> adjacency + degree =================
__global__ __launch_bounds__(256) void k_corr(
    const float* __restrict__ Xn, const float* __restrict__ XnT,
    float* __restrict__ A, float* __restrict__ deg)
{
    const int i = blockIdx.x, tid = threadIdx.x;
    __shared__ float xi[128];
    __shared__ float red[256];
    if (tid < 128) xi[tid] = Xn[i * 128 + tid];
    __syncthreads();
    float c = 0.f;
    for (int k = 0; k < 128; ++k) c += xi[k] * XnT[k * 256 + tid];
    c *= (1.0f / 128.0f);
    float a = (fabsf(c) > 0.7f) ? 1.0f : 0.0f;
    A[i * 256 + tid] = a;
    red[tid] = a;
    __syncthreads();
    for (int s = 128; s > 0; s >>= 1) { if (tid < s) red[tid] += red[tid + s]; __syncthreads(); }
    if (tid == 0) deg[i] = red[0];
}

// ================= K3c/d: GCN layer (+ optional next-layer feature GEMM) =====
__global__ __launch_bounds__(256) void k_gcn(
    const float* __restrict__ A, const float* __restrict__ deg,
    const float* __restrict__ hw, const float* __restrict__ bias,
    const float* __restrict__ wNext,
    float* __restrict__ hOut, float* __restrict__ hwNext)
{
    const int i = blockIdx.x, tid = threadIdx.x;
    const int f = tid & 31, grp = tid >> 5;
    __shared__ float aj[256];
    __shared__ float red[8][32];
    __shared__ float hrow[32];
    float dj = rsqrtf(fmaxf(deg[tid], 1e-12f));
    aj[tid] = A[i * 256 + tid] * dj;
    __syncthreads();
    float p = 0.f;
    for (int j = grp * 32; j < grp * 32 + 32; ++j) p += aj[j] * hw[j * 32 + f];
    red[grp][f] = p;
    __syncthreads();
    if (grp == 0) {
        float s = 0.f;
        #pragma unroll
        for (int g = 0; g < 8; ++g) s += red[g][f];
        float di = rsqrtf(fmaxf(deg[i], 1e-12f));
        float o = fmaxf(bias[f] + di * s, 0.0f);
        hOut[i * 32 + f] = o;
        hrow[f] = o;
    }
    __syncthreads();
    if (wNext != nullptr && grp == 0) {
        float acc = 0.f;
        #pragma unroll
        for (int k = 0; k < 32; ++k) acc += hrow[k] * wNext[f * 32 + k];
        hwNext[i * 32 + f] = acc;
    }
}

// ================= K3e: mean + classifier =================
__global__ __launch_bounds__(64) void k_head(
    const float* __restrict__ h2, const float* __restrict__ cls_w,
    const float* __restrict__ cls_b, float* __restrict__ out)
{
    const int tid = threadIdx.x;
    __shared__ float mean[32];
    if (tid < 32) {
        float s = 0.f;
        for (int i = 0; i < 256; ++i) s += h2[i * 32 + tid];
        mean[tid] = s * (1.0f / 256.0f);
    }
    __syncthreads();
    if (tid < 2) {
        float s = cls_b[tid];
        #pragma unroll
        for (int fe = 0; fe < 32; ++fe) s += mean[fe] * cls_w[tid * 32 + fe];
        out[tid] = s;
    }
}

extern "C" void kernel_launch(void* const* d_in, const int* in_sizes, int n_in,
                              void* d_out, int out_size, void* d_ws, size_t ws_size,
                              hipStream_t stream) {
    const float* data    = (const float*)d_in[0];
    const float* conv1_w = (const float*)d_in[1];
    const float* conv1_b = (const float*)d_in[2];
    const float* conv2_w = (const float*)d_in[3];
    const float* conv2_b = (const float*)d_in[4];
    const float* conv3_w = (const float*)d_in[5];
    const float* conv3_b = (const float*)d_in[6];
    const float* wih_f   = (const float*)d_in[7];
    const float* whh_f   = (const float*)d_in[8];
    const float* bih_f   = (const float*)d_in[9];
    const float* bhh_f   = (const float*)d_in[10];
    const float* wih_b   = (const float*)d_in[11];
    const float* whh_b   = (const float*)d_in[12];
    const float* bih_b   = (const float*)d_in[13];
    const float* bhh_b   = (const float*)d_in[14];
    const float* gcn1_w  = (const float*)d_in[15];
    const float* gcn1_b  = (const float*)d_in[16];
    const float* gcn2_w  = (const float*)d_in[17];
    const float* gcn2_b  = (const float*)d_in[18];
    const float* cls_w   = (const float*)d_in[19];
    const float* cls_b   = (const float*)d_in[20];

    float* ws  = (float*)d_ws;
    float* x3  = ws;                   // 256*800*32 = 6,553,600
    float* hN  = x3 + 6553600;         // 256*128
    float* Xn  = hN + 32768;           // 256*128
    float* XnT = Xn + 32768;           // 128*256
    float* A   = XnT + 32768;          // 256*256
    float* deg = A + 65536;            // 256
    float* hw1 = deg + 256;            // 256*32
    float* h1  = hw1 + 8192;           // 256*32
    float* hw2 = h1 + 8192;            // 256*32
    float* h2  = hw2 + 8192;           // 256*32

    k_conv<<<dim3(32, 256), 256, 0, stream>>>(data, conv1_w, conv1_b, conv2_w, conv2_b,
                                              conv3_w, conv3_b, x3);
    k_gru<<<dim3(256, 2), 64, 0, stream>>>(x3, wih_f, whh_f, bih_f, bhh_f,
                                           wih_b, whh_b, bih_b, bhh_b, hN);
    k_norm<<<256, 128, 0, stream>>>(hN, gcn1_w, Xn, XnT, hw1);
    k_corr<<<256, 256, 0, stream>>>(Xn, XnT, A, deg);
    k_gcn<<<256, 256, 0, stream>>>(A, deg, hw1, gcn1_b, gcn2_w, h1, hw2);
    k_gcn<<<256, 256, 0, stream>>>(A, deg, hw2, gcn2_b, nullptr, h2, nullptr);
    k_head<<<1, 64, 0, stream>>>(h2, cls_w, cls_b, (float*)d_out);
}

// Round 2
// 1219.722 us; speedup vs baseline: 1.1817x; 1.1817x over previous
//
#include <hip/hip_runtime.h>
#include <math.h>

#define N_CH 256
#define T_IN 100000
#define L1O 20000
#define L2O 4000
#define L3O 800
#define C1 8
#define C2 16
#define C3 32

// ---------- fused conv tile geometry ----------
#define TILE3 25      // conv3 outputs per block
#define NY2   125     // conv2 positions needed
#define NY1   627     // conv1 positions needed
#define ND    3141    // data samples needed

__device__ __forceinline__ float sigm(float x) {
    x = fminf(fmaxf(x, -30.0f), 30.0f);
    return 1.0f / (1.0f + __expf(-x));
}
__device__ __forceinline__ float tanhfast(float x) {
    x = fminf(fmaxf(x, -15.0f), 15.0f);
    float e = __expf(-2.0f * x);
    return (1.0f - e) / (1.0f + e);
}
__device__ __forceinline__ float dot4(float4 a, float4 b) {
    return a.x * b.x + a.y * b.y + a.z * b.z + a.w * b.w;
}

// ================= K1: fused conv1+conv2+conv3 =================
// grid (32 tiles, 256 channels), 256 threads
__global__ __launch_bounds__(256) void k_conv(
    const float* __restrict__ data,
    const float* __restrict__ w1, const float* __restrict__ b1,
    const float* __restrict__ w2, const float* __restrict__ b2,
    const float* __restrict__ w3, const float* __restrict__ b3,
    float* __restrict__ x3)
{
    __shared__ __align__(16) float sd[ND];
    __shared__ __align__(16) float sy1[NY1][C1];
    __shared__ __align__(16) float sy2[NY2][C2];
    __shared__ __align__(16) float sw1[C1 * 11];
    __shared__ float sb1[C1];
    __shared__ __align__(16) float sw2[C2 * C1 * 7];
    __shared__ float sb2[C2];
    __shared__ __align__(16) float sw3[C3 * C2 * 5];
    __shared__ float sb3[C3];

    const int tid = threadIdx.x;
    const int tb  = blockIdx.x;   // tile
    const int ch  = blockIdx.y;   // channel
    const int t0    = tb * TILE3;
    const int dbase = 3125 * tb - 70;
    const int ubase = 625 * tb - 13;
    const int sbase = 125 * tb - 2;

    for (int e = tid; e < C1 * 11;    e += 256) sw1[e] = w1[e];
    for (int e = tid; e < C1;         e += 256) sb1[e] = b1[e];
    for (int e = tid; e < C2 * C1 * 7; e += 256) sw2[e] = w2[e];
    for (int e = tid; e < C2;         e += 256) sb2[e] = b2[e];
    for (int e = tid; e < C3 * C2 * 5; e += 256) sw3[e] = w3[e];
    for (int e = tid; e < C3;         e += 256) sb3[e] = b3[e];

    const float* dch = data + (size_t)ch * T_IN;
    for (int e = tid; e < ND; e += 256) {
        int g = dbase + e;
        sd[e] = (g >= 0 && g < T_IN) ? dch[g] : 0.0f;
    }
    __syncthreads();

    // conv1 (stride 5, k=11, pad 5): thread owns out-channel c = tid&7
    {
        const int c = tid & 7;
        float wr[11];
        #pragma unroll
        for (int k = 0; k < 11; ++k) wr[k] = sw1[c * 11 + k];
        const float bb = sb1[c];
        for (int u = tid >> 3; u < NY1; u += 32) {
            int ug = ubase + u;
            float acc = bb;
            #pragma unroll
            for (int k = 0; k < 11; ++k) acc += wr[k] * sd[5 * u + k];
            sy1[u][c] = (ug >= 0 && ug < L1O) ? fmaxf(acc, 0.0f) : 0.0f;
        }
    }
    __syncthreads();

    // conv2 (stride 5, k=7, pad 3): thread owns out-channel c = tid&15
    {
        const int c = tid & 15;
        float wr[56];
        #pragma unroll
        for (int q = 0; q < 14; ++q)
            ((float4*)wr)[q] = ((const float4*)(sw2 + c * 56))[q];
        const float bb = sb2[c];
        for (int s = tid >> 4; s < NY2; s += 16) {
            int sg = sbase + s;
            float acc = bb;
            #pragma unroll
            for (int k = 0; k < 7; ++k) {
                const float4* y4 = (const float4*)&sy1[5 * s + k][0];
                float4 ya = y4[0], yb = y4[1];
                acc += wr[0*7+k]*ya.x + wr[1*7+k]*ya.y + wr[2*7+k]*ya.z + wr[3*7+k]*ya.w
                     + wr[4*7+k]*yb.x + wr[5*7+k]*yb.y + wr[6*7+k]*yb.z + wr[7*7+k]*yb.w;
            }
            sy2[s][c] = (sg >= 0 && sg < L2O) ? fmaxf(acc, 0.0f) : 0.0f;
        }
    }
    __syncthreads();

    // conv3 (stride 5, k=5, pad 2): thread owns out-channel o = tid&31
    {
        const int o = tid & 31;
        float wr[80];
        #pragma unroll
        for (int q = 0; q < 20; ++q)
            ((float4*)wr)[q] = ((const float4*)(sw3 + o * 80))[q];
        const float bb = sb3[o];
        for (int tl = tid >> 5; tl < TILE3; tl += 8) {
            float acc = bb;
            #pragma unroll
            for (int k = 0; k < 5; ++k) {
                const float4* y4 = (const float4*)&sy2[5 * tl + k][0];
                float4 za = y4[0], zb = y4[1], zc = y4[2], zd = y4[3];
                acc += wr[0*5+k]*za.x  + wr[1*5+k]*za.y  + wr[2*5+k]*za.z  + wr[3*5+k]*za.w
                     + wr[4*5+k]*zb.x  + wr[5*5+k]*zb.y  + wr[6*5+k]*zb.z  + wr[7*5+k]*zb.w
                     + wr[8*5+k]*zc.x  + wr[9*5+k]*zc.y  + wr[10*5+k]*zc.z + wr[11*5+k]*zc.w
                     + wr[12*5+k]*zd.x + wr[13*5+k]*zd.y + wr[14*5+k]*zd.z + wr[15*5+k]*zd.w;
            }
            x3[((size_t)ch * L3O + (t0 + tl)) * C3 + o] = fmaxf(acc, 0.0f);
        }
    }
}

// ================= K1b: Gi = x3 @ wih.T + bih (recurrence order) ===========
// grid (512 dirch, CH/25), block 192: thread = gate row, weights in regs
__global__ __launch_bounds__(192) void k_gi(
    const float* __restrict__ x3,
    const float* __restrict__ wih_f, const float* __restrict__ bih_f,
    const float* __restrict__ wih_b, const float* __restrict__ bih_b,
    float* __restrict__ Gi, int c0, int CH)
{
    const int row = threadIdx.x;                  // 0..191
    const int dirch = blockIdx.x;
    const int dir = dirch >> 8, ch = dirch & 255;
    const int tt0 = blockIdx.y * 25;
    const float* wih = dir ? wih_b : wih_f;
    const float* bih = dir ? bih_b : bih_f;
    __shared__ __align__(16) float sx[25][32];

    for (int e = row; e < 25 * 32; e += 192) {
        int tt = e >> 5, k = e & 31;
        int step = c0 + tt0 + tt;
        int tm = dir ? (L3O - 1 - step) : step;
        sx[tt][k] = x3[((size_t)ch * L3O + tm) * 32 + k];
    }
    float4 w[8];
    const float4* w4 = (const float4*)(wih + row * 32);
    #pragma unroll
    for (int q = 0; q < 8; ++q) w[q] = w4[q];
    const float bb = bih[row];
    __syncthreads();

    float* gout = Gi + ((size_t)dirch * CH + tt0) * 192 + row;
    for (int tt = 0; tt < 25; ++tt) {
        const float4* x4 = (const float4*)&sx[tt][0];
        float a0 = 0, a1 = 0, a2 = 0, a3 = 0;
        #pragma unroll
        for (int q = 0; q < 8; q += 4) {
            a0 += dot4(w[q],     x4[q]);
            a1 += dot4(w[q + 1], x4[q + 1]);
            a2 += dot4(w[q + 2], x4[q + 2]);
            a3 += dot4(w[q + 3], x4[q + 3]);
        }
        gout[tt * 192] = bb + ((a0 + a1) + (a2 + a3));
    }
}

// ================= K2: GRU recurrence (gi precomputed), 1 wave/(ch,dir) ====
__global__ __launch_bounds__(64, 1) void k_gru2(
    const float* __restrict__ Gi,
    const float* __restrict__ whh_f, const float* __restrict__ bhh_f,
    const float* __restrict__ whh_b, const float* __restrict__ bhh_b,
    float* __restrict__ hN, int t0, int tlen, int CH)
{
    const int lane = threadIdx.x;
    const int ch = blockIdx.x, dir = blockIdx.y;
    const int dirch = dir * 256 + ch;
    const float* whh = dir ? whh_b : whh_f;
    const float* bhh = dir ? bhh_b : bhh_f;
    __shared__ __align__(16) float sh[64];

    float4 whr[16], whz[16], whn[16];
    const float4* whh4 = (const float4*)whh;
    #pragma unroll
    for (int j = 0; j < 16; ++j) {
        whr[j] = whh4[(0   + lane) * 16 + j];
        whz[j] = whh4[(64  + lane) * 16 + j];
        whn[j] = whh4[(128 + lane) * 16 + j];
    }
    const float bhr = bhh[lane], bhz = bhh[64 + lane], bhn = bhh[128 + lane];

    float h = (t0 == 0) ? 0.0f : hN[ch * 128 + dir * 64 + lane];
    sh[lane] = h;
    __syncthreads();

    const float* gp = Gi + (size_t)dirch * CH * 192;
    float gr = gp[lane], gz = gp[64 + lane], gn = gp[128 + lane];
    for (int tl = 0; tl < tlen; ++tl) {
        const float* gpn = gp + 192;
        float grn = 0.f, gzn = 0.f, gnn = 0.f;
        if (tl + 1 < tlen) { grn = gpn[lane]; gzn = gpn[64 + lane]; gnn = gpn[128 + lane]; }

        float hr0=0,hr1=0,hr2=0,hr3=0, hz0=0,hz1=0,hz2=0,hz3=0, hn0=0,hn1=0,hn2=0,hn3=0;
        const float4* sh4 = (const float4*)sh;
        #pragma unroll
        for (int j = 0; j < 16; j += 4) {
            float4 a = sh4[j], b = sh4[j+1], c = sh4[j+2], d = sh4[j+3];
            hr0 += dot4(whr[j],   a); hr1 += dot4(whr[j+1], b);
            hr2 += dot4(whr[j+2], c); hr3 += dot4(whr[j+3], d);
            hz0 += dot4(whz[j],   a); hz1 += dot4(whz[j+1], b);
            hz2 += dot4(whz[j+2], c); hz3 += dot4(whz[j+3], d);
            hn0 += dot4(whn[j],   a); hn1 += dot4(whn[j+1], b);
            hn2 += dot4(whn[j+2], c); hn3 += dot4(whn[j+3], d);
        }
        float r = sigm(gr + bhr + ((hr0 + hr1) + (hr2 + hr3)));
        float z = sigm(gz + bhz + ((hz0 + hz1) + (hz2 + hz3)));
        float hnv = ((hn0 + hn1) + (hn2 + hn3)) + bhn;
        float n = tanhfast(gn + r * hnv);
        h = (1.0f - z) * n + z * h;
        __syncthreads();
        sh[lane] = h;
        __syncthreads();
        gr = grn; gz = gzn; gn = gnn; gp = gpn;
    }
    hN[ch * 128 + dir * 64 + lane] = h;
}

// ================= K2-fallback: original in-kernel GRU =================
#define CHUNK 100
__global__ __launch_bounds__(64) void k_gru(
    const float* __restrict__ x3,
    const float* __restrict__ wih_f, const float* __restrict__ whh_f,
    const float* __restrict__ bih_f, const float* __restrict__ bhh_f,
    const float* __restrict__ wih_b, const float* __restrict__ whh_b,
    const float* __restrict__ bih_b, const float* __restrict__ bhh_b,
    float* __restrict__ hN)
{
    const int lane = threadIdx.x;
    const int ch   = blockIdx.x;
    const int dir  = blockIdx.y;
    const float* wih = dir ? wih_b : wih_f;
    const float* whh = dir ? whh_b : whh_f;
    const float* bih = dir ? bih_b : bih_f;
    const float* bhh = dir ? bhh_b : bhh_f;

    __shared__ __align__(16) float sh[64];
    __shared__ __align__(16) float sx[CHUNK * 32];

    float4 wir[8], wiz[8], win[8];
    const float4* wih4 = (const float4*)wih;
    #pragma unroll
    for (int k = 0; k < 8; ++k) {
        wir[k] = wih4[(0   + lane) * 8 + k];
        wiz[k] = wih4[(64  + lane) * 8 + k];
        win[k] = wih4[(128 + lane) * 8 + k];
    }
    float4 whr[16], whz[16], whn[16];
    const float4* whh4 = (const float4*)whh;
    #pragma unroll
    for (int j = 0; j < 16; ++j) {
        whr[j] = whh4[(0   + lane) * 16 + j];
        whz[j] = whh4[(64  + lane) * 16 + j];
        whn[j] = whh4[(128 + lane) * 16 + j];
    }
    const float bir = bih[lane], biz = bih[64 + lane], bin_ = bih[128 + lane];
    const float bhr = bhh[lane], bhz = bhh[64 + lane], bhn  = bhh[128 + lane];

    float h = 0.0f;
    sh[lane] = 0.0f;
    __syncthreads();

    const float* xch = x3 + (size_t)ch * L3O * 32;
    for (int c0 = 0; c0 < L3O; c0 += CHUNK) {
        for (int e = lane; e < CHUNK * 32; e += 64) {
            int tt = e >> 5, k = e & 31;
            int sidx = c0 + tt;
            int t = dir ? (L3O - 1 - sidx) : sidx;
            sx[e] = xch[t * 32 + k];
        }
        __syncthreads();
        for (int tl = 0; tl < CHUNK; ++tl) {
            const float4* xv4 = (const float4*)(sx + tl * 32);
            float gr = 0.f, gz = 0.f, gn = 0.f;
            #pragma unroll
            for (int k = 0; k < 8; ++k) {
                float4 x4 = xv4[k];
                gr += dot4(wir[k], x4); gz += dot4(wiz[k], x4); gn += dot4(win[k], x4);
            }
            float hr = 0.f, hz = 0.f, hn = 0.f;
            const float4* sh4 = (const float4*)sh;
            #pragma unroll
            for (int j = 0; j < 16; ++j) {
                float4 h4 = sh4[j];
                hr += dot4(whr[j], h4); hz += dot4(whz[j], h4); hn += dot4(whn[j], h4);
            }
            float r = sigm(gr + bir + hr + bhr);
            float z = sigm(gz + biz + hz + bhz);
            float n = tanhfast(gn + bin_ + r * (hn + bhn));
            h = (1.0f - z) * n + z * h;
            __syncthreads();
            sh[lane] = h;
            __syncthreads();
        }
    }
    hN[ch * 128 + dir * 64 + lane] = h;
}

// ================= K3a: row normalize + hw1 = h_n @ gcn1_w.T =================
__global__ __launch_bounds__(128) void k_norm(
    const float* __restrict__ hN, const float* __restrict__ gcn1_w,
    float* __restrict__ Xn, float* __restrict__ XnT, float* __restrict__ hw1)
{
    const int i = blockIdx.x, tid = threadIdx.x;
    __shared__ float red[128];
    __shared__ float row[128];
    float v = hN[i * 128 + tid];
    row[tid] = v;
    red[tid] = v;
    __syncthreads();
    for (int s = 64; s > 0; s >>= 1) { if (tid < s) red[tid] += red[tid + s]; __syncthreads(); }
    float mean = red[0] / 128.0f;
    __syncthreads();
    float d = v - mean;
    red[tid] = d * d;
    __syncthreads();
    for (int s = 64; s > 0; s >>= 1) { if (tid < s) red[tid] += red[tid + s]; __syncthreads(); }
    float sd = sqrtf(red[0] / 127.0f);
    float xn = d / (sd + 1e-6f);
    Xn[i * 128 + tid] = xn;
    XnT[tid * 256 + i] = xn;
    if (tid < 32) {
        float acc = 0.f;
        for (int k = 0; k < 128; ++k) acc += row[k] * gcn1_w[tid * 128 + k];
        hw1[i * 32 + tid] = acc;
    }
}

// ================= K3b: corr row -> adjacency + degree =================
__global__ __launch_bounds__(256) void k_corr(
    const float* __restrict__ Xn, const float* __restrict__ XnT,
    float* __restrict__ A, float* __restrict__ deg)
{
    const int i = blockIdx.x, tid = threadIdx.x;
    __shared__ float xi[128];
    __shared__ float red[256];
    if (tid < 128) xi[tid] = Xn[i * 128 + tid];
    __syncthreads();
    float c = 0.f;
    for (int k = 0; k < 128; ++k) c += xi[k] * XnT[k * 256 + tid];
    c *= (1.0f / 128.0f);
    float a = (fabsf(c) > 0.7f) ? 1.0f : 0.0f;
    A[i * 256 + tid] = a;
    red[tid] = a;
    __syncthreads();
    for (int s = 128; s > 0; s >>= 1) { if (tid < s) red[tid] += red[tid + s]; __syncthreads(); }
    if (tid == 0) deg[i] = red[0];
}

// ================= K3c/d: GCN layer (+ optional next-layer feature GEMM) =====
__global__ __launch_bounds__(256) void k_gcn(
    const float* __restrict__ A, const float* __restrict__ deg,
    const float* __restrict__ hw, const float* __restrict__ bias,
    const float* __restrict__ wNext,
    float* __restrict__ hOut, float* __restrict__ hwNext)
{
    const int i = blockIdx.x, tid = threadIdx.x;
    const int f = tid & 31, grp = tid >> 5;
    __shared__ float aj[256];
    __shared__ float red[8][32];
    __shared__ float hrow[32];
    float dj = rsqrtf(fmaxf(deg[tid], 1e-12f));
    aj[tid] = A[i * 256 + tid] * dj;
    __syncthreads();
    float p = 0.f;
    for (int j = grp * 32; j < grp * 32 + 32; ++j) p += aj[j] * hw[j * 32 + f];
    red[grp][f] = p;
    __syncthreads();
    if (grp == 0) {
        float s = 0.f;
        #pragma unroll
        for (int g = 0; g < 8; ++g) s += red[g][f];
        float di = rsqrtf(fmaxf(deg[i], 1e-12f));
        float o = fmaxf(bias[f] + di * s, 0.0f);
        hOut[i * 32 + f] = o;
        hrow[f] = o;
    }
    __syncthreads();
    if (wNext != nullptr && grp == 0) {
        float acc = 0.f;
        #pragma unroll
        for (int k = 0; k < 32; ++k) acc += hrow[k] * wNext[f * 32 + k];
        hwNext[i * 32 + f] = acc;
    }
}

// ================= K3e: mean + classifier =================
__global__ __launch_bounds__(64) void k_head(
    const float* __restrict__ h2, const float* __restrict__ cls_w,
    const float* __restrict__ cls_b, float* __restrict__ out)
{
    const int tid = threadIdx.x;
    __shared__ float mean[32];
    if (tid < 32) {
        float s = 0.f;
        for (int i = 0; i < 256; ++i) s += h2[i * 32 + tid];
        mean[tid] = s * (1.0f / 256.0f);
    }
    __syncthreads();
    if (tid < 2) {
        float s = cls_b[tid];
        #pragma unroll
        for (int fe = 0; fe < 32; ++fe) s += mean[fe] * cls_w[tid * 32 + fe];
        out[tid] = s;
    }
}

extern "C" void kernel_launch(void* const* d_in, const int* in_sizes, int n_in,
                              void* d_out, int out_size, void* d_ws, size_t ws_size,
                              hipStream_t stream) {
    const float* data    = (const float*)d_in[0];
    const float* conv1_w = (const float*)d_in[1];
    const float* conv1_b = (const float*)d_in[2];
    const float* conv2_w = (const float*)d_in[3];
    const float* conv2_b = (const float*)d_in[4];
    const float* conv3_w = (const float*)d_in[5];
    const float* conv3_b = (const float*)d_in[6];
    const float* wih_f   = (const float*)d_in[7];
    const float* whh_f   = (const float*)d_in[8];
    const float* bih_f   = (const float*)d_in[9];
    const float* bhh_f   = (const float*)d_in[10];
    const float* wih_b   = (const float*)d_in[11];
    const float* whh_b   = (const float*)d_in[12];
    const float* bih_b   = (const float*)d_in[13];
    const float* bhh_b   = (const float*)d_in[14];
    const float* gcn1_w  = (const float*)d_in[15];
    const float* gcn1_b  = (const float*)d_in[16];
    const float* gcn2_w  = (const float*)d_in[17];
    const float* gcn2_b  = (const float*)d_in[18];
    const float* cls_w   = (const float*)d_in[19];
    const float* cls_b   = (const float*)d_in[20];

    float* ws  = (float*)d_ws;
    float* x3  = ws;                   // 256*800*32 = 6,553,600
    float* hN  = x3 + 6553600;         // 256*128
    float* Xn  = hN + 32768;           // 256*128
    float* XnT = Xn + 32768;           // 128*256
    float* A   = XnT + 32768;          // 256*256
    float* deg = A + 65536;            // 256
    float* hw1 = deg + 256;            // 256*32
    float* h1  = hw1 + 8192;           // 256*32
    float* hw2 = h1 + 8192;            // 256*32
    float* h2  = hw2 + 8192;           // 256*32
    float* Gi  = h2 + 8192;            // 512*CH*192 (variable)

    const size_t BASE = 6726272;       // floats used before Gi
    const size_t avail = ws_size / 4;
    int CH = 0;
    if      (avail >= BASE + (size_t)512 * 800 * 192) CH = 800;
    else if (avail >= BASE + (size_t)512 * 100 * 192) CH = 100;
    else if (avail >= BASE + (size_t)512 *  50 * 192) CH = 50;
    else if (avail >= BASE + (size_t)512 *  25 * 192) CH = 25;

    k_conv<<<dim3(32, 256), 256, 0, stream>>>(data, conv1_w, conv1_b, conv2_w, conv2_b,
                                              conv3_w, conv3_b, x3);
    if (CH) {
        for (int c0 = 0; c0 < L3O; c0 += CH) {
            k_gi<<<dim3(512, CH / 25), 192, 0, stream>>>(x3, wih_f, bih_f, wih_b, bih_b,
                                                         Gi, c0, CH);
            k_gru2<<<dim3(256, 2), 64, 0, stream>>>(Gi, whh_f, bhh_f, whh_b, bhh_b,
                                                    hN, c0, CH, CH);
        }
    } else {
        k_gru<<<dim3(256, 2), 64, 0, stream>>>(x3, wih_f, whh_f, bih_f, bhh_f,
                                               wih_b, whh_b, bih_b, bhh_b, hN);
    }
    k_norm<<<256, 128, 0, stream>>>(hN, gcn1_w, Xn, XnT, hw1);
    k_corr<<<256, 256, 0, stream>>>(Xn, XnT, A, deg);
    k_gcn<<<256, 256, 0, stream>>>(A, deg, hw1, gcn1_b, gcn2_w, h1, hw2);
    k_gcn<<<256, 256, 0, stream>>>(A, deg, hw2, gcn2_b, nullptr, h2, nullptr);
    k_head<<<1, 64, 0, stream>>>(h2, cls_w, cls_b, (float*)d_out);
}

// Round 3
// 977.656 us; speedup vs baseline: 1.4743x; 1.2476x over previous
//
#include <hip/hip_runtime.h>
#include <math.h>

#define N_CH 256
#define T_IN 100000
#define L1O 20000
#define L2O 4000
#define L3O 800
#define C1 8
#define C2 16
#define C3 32

// ---------- fused conv tile geometry ----------
#define TILE3 25      // conv3 outputs per block
#define NY2   125     // conv2 positions needed
#define NY1   627     // conv1 positions needed
#define ND    3141    // data samples needed

#define KEEP1(x) asm volatile("" : "+v"(x))

__device__ __forceinline__ float sigm(float x) {
    x = fminf(fmaxf(x, -30.0f), 30.0f);
    return 1.0f / (1.0f + __expf(-x));
}
__device__ __forceinline__ float tanhfast(float x) {
    x = fminf(fmaxf(x, -15.0f), 15.0f);
    float e = __expf(-2.0f * x);
    return (1.0f - e) / (1.0f + e);
}
__device__ __forceinline__ float dot4(float4 a, float4 b) {
    return a.x * b.x + a.y * b.y + a.z * b.z + a.w * b.w;
}
__device__ __forceinline__ float bcast(float v, int lane) {
    return __int_as_float(__builtin_amdgcn_readlane(__float_as_int(v), lane));
}

// ================= K1: fused conv1+conv2+conv3 =================
// grid (32 tiles, 256 channels), 256 threads
__global__ __launch_bounds__(256) void k_conv(
    const float* __restrict__ data,
    const float* __restrict__ w1, const float* __restrict__ b1,
    const float* __restrict__ w2, const float* __restrict__ b2,
    const float* __restrict__ w3, const float* __restrict__ b3,
    float* __restrict__ x3)
{
    __shared__ __align__(16) float sd[ND];
    __shared__ __align__(16) float sy1[NY1][C1];
    __shared__ __align__(16) float sy2[NY2][C2];
    __shared__ __align__(16) float sw1[C1 * 11];
    __shared__ float sb1[C1];
    __shared__ __align__(16) float sw2[C2 * C1 * 7];
    __shared__ float sb2[C2];
    __shared__ __align__(16) float sw3[C3 * C2 * 5];
    __shared__ float sb3[C3];

    const int tid = threadIdx.x;
    const int tb  = blockIdx.x;   // tile
    const int ch  = blockIdx.y;   // channel
    const int t0    = tb * TILE3;
    const int dbase = 3125 * tb - 70;
    const int ubase = 625 * tb - 13;
    const int sbase = 125 * tb - 2;

    for (int e = tid; e < C1 * 11;    e += 256) sw1[e] = w1[e];
    for (int e = tid; e < C1;         e += 256) sb1[e] = b1[e];
    for (int e = tid; e < C2 * C1 * 7; e += 256) sw2[e] = w2[e];
    for (int e = tid; e < C2;         e += 256) sb2[e] = b2[e];
    for (int e = tid; e < C3 * C2 * 5; e += 256) sw3[e] = w3[e];
    for (int e = tid; e < C3;         e += 256) sb3[e] = b3[e];

    const float* dch = data + (size_t)ch * T_IN;
    for (int e = tid; e < ND; e += 256) {
        int g = dbase + e;
        sd[e] = (g >= 0 && g < T_IN) ? dch[g] : 0.0f;
    }
    __syncthreads();

    // conv1 (stride 5, k=11, pad 5): thread owns out-channel c = tid&7
    {
        const int c = tid & 7;
        float wr[11];
        #pragma unroll
        for (int k = 0; k < 11; ++k) wr[k] = sw1[c * 11 + k];
        const float bb = sb1[c];
        for (int u = tid >> 3; u < NY1; u += 32) {
            int ug = ubase + u;
            float acc = bb;
            #pragma unroll
            for (int k = 0; k < 11; ++k) acc += wr[k] * sd[5 * u + k];
            sy1[u][c] = (ug >= 0 && ug < L1O) ? fmaxf(acc, 0.0f) : 0.0f;
        }
    }
    __syncthreads();

    // conv2 (stride 5, k=7, pad 3): thread owns out-channel c = tid&15
    {
        const int c = tid & 15;
        float wr[56];
        #pragma unroll
        for (int q = 0; q < 14; ++q)
            ((float4*)wr)[q] = ((const float4*)(sw2 + c * 56))[q];
        const float bb = sb2[c];
        for (int s = tid >> 4; s < NY2; s += 16) {
            int sg = sbase + s;
            float acc = bb;
            #pragma unroll
            for (int k = 0; k < 7; ++k) {
                const float4* y4 = (const float4*)&sy1[5 * s + k][0];
                float4 ya = y4[0], yb = y4[1];
                acc += wr[0*7+k]*ya.x + wr[1*7+k]*ya.y + wr[2*7+k]*ya.z + wr[3*7+k]*ya.w
                     + wr[4*7+k]*yb.x + wr[5*7+k]*yb.y + wr[6*7+k]*yb.z + wr[7*7+k]*yb.w;
            }
            sy2[s][c] = (sg >= 0 && sg < L2O) ? fmaxf(acc, 0.0f) : 0.0f;
        }
    }
    __syncthreads();

    // conv3 (stride 5, k=5, pad 2): thread owns out-channel o = tid&31
    {
        const int o = tid & 31;
        float wr[80];
        #pragma unroll
        for (int q = 0; q < 20; ++q)
            ((float4*)wr)[q] = ((const float4*)(sw3 + o * 80))[q];
        const float bb = sb3[o];
        for (int tl = tid >> 5; tl < TILE3; tl += 8) {
            float acc = bb;
            #pragma unroll
            for (int k = 0; k < 5; ++k) {
                const float4* y4 = (const float4*)&sy2[5 * tl + k][0];
                float4 za = y4[0], zb = y4[1], zc = y4[2], zd = y4[3];
                acc += wr[0*5+k]*za.x  + wr[1*5+k]*za.y  + wr[2*5+k]*za.z  + wr[3*5+k]*za.w
                     + wr[4*5+k]*zb.x  + wr[5*5+k]*zb.y  + wr[6*5+k]*zb.z  + wr[7*5+k]*zb.w
                     + wr[8*5+k]*zc.x  + wr[9*5+k]*zc.y  + wr[10*5+k]*zc.z + wr[11*5+k]*zc.w
                     + wr[12*5+k]*zd.x + wr[13*5+k]*zd.y + wr[14*5+k]*zd.z + wr[15*5+k]*zd.w;
            }
            x3[((size_t)ch * L3O + (t0 + tl)) * C3 + o] = fmaxf(acc, 0.0f);
        }
    }
}

// ================= K1b: Gi = x3 @ wih.T + bih (recurrence order) ===========
// grid (512 dirch, CH/25), block 192: thread = gate row, weights in regs
__global__ __launch_bounds__(192) void k_gi(
    const float* __restrict__ x3,
    const float* __restrict__ wih_f, const float* __restrict__ bih_f,
    const float* __restrict__ wih_b, const float* __restrict__ bih_b,
    float* __restrict__ Gi, int c0, int CH)
{
    const int row = threadIdx.x;                  // 0..191
    const int dirch = blockIdx.x;
    const int dir = dirch >> 8, ch = dirch & 255;
    const int tt0 = blockIdx.y * 25;
    const float* wih = dir ? wih_b : wih_f;
    const float* bih = dir ? bih_b : bih_f;
    __shared__ __align__(16) float sx[25][32];

    for (int e = row; e < 25 * 32; e += 192) {
        int tt = e >> 5, k = e & 31;
        int step = c0 + tt0 + tt;
        int tm = dir ? (L3O - 1 - step) : step;
        sx[tt][k] = x3[((size_t)ch * L3O + tm) * 32 + k];
    }
    float4 w[8];
    const float4* w4 = (const float4*)(wih + row * 32);
    #pragma unroll
    for (int q = 0; q < 8; ++q) w[q] = w4[q];
    const float bb = bih[row];
    __syncthreads();

    float* gout = Gi + ((size_t)dirch * CH + tt0) * 192 + row;
    for (int tt = 0; tt < 25; ++tt) {
        const float4* x4 = (const float4*)&sx[tt][0];
        float a0 = 0, a1 = 0, a2 = 0, a3 = 0;
        #pragma unroll
        for (int q = 0; q < 8; q += 4) {
            a0 += dot4(w[q],     x4[q]);
            a1 += dot4(w[q + 1], x4[q + 1]);
            a2 += dot4(w[q + 2], x4[q + 2]);
            a3 += dot4(w[q + 3], x4[q + 3]);
        }
        gout[tt * 192] = bb + ((a0 + a1) + (a2 + a3));
    }
}

// ================= K2: GRU recurrence — readlane broadcast, no LDS ==========
// 1 wave per (ch,dir); lane owns h[lane]; weights pinned in VGPRs.
__global__ __launch_bounds__(64, 1) void k_gru3(
    const float* __restrict__ Gi,
    const float* __restrict__ whh_f, const float* __restrict__ bhh_f,
    const float* __restrict__ whh_b, const float* __restrict__ bhh_b,
    float* __restrict__ hN, int t0, int tlen, int CH)
{
    const int lane = threadIdx.x;
    const int ch = blockIdx.x, dir = blockIdx.y;
    const int dirch = dir * 256 + ch;
    const float* whh = dir ? whh_b : whh_f;
    const float* bhh = dir ? bhh_b : bhh_f;

    // row `lane` of each gate's 64x64 block, as 192 scalars pinned in VGPRs
    float wr[64], wz[64], wn[64];
    const float4* whh4 = (const float4*)whh;
    #pragma unroll
    for (int q = 0; q < 16; ++q) {
        float4 a = whh4[(0   + lane) * 16 + q];
        float4 b = whh4[(64  + lane) * 16 + q];
        float4 c = whh4[(128 + lane) * 16 + q];
        wr[4*q] = a.x; wr[4*q+1] = a.y; wr[4*q+2] = a.z; wr[4*q+3] = a.w;
        wz[4*q] = b.x; wz[4*q+1] = b.y; wz[4*q+2] = b.z; wz[4*q+3] = b.w;
        wn[4*q] = c.x; wn[4*q+1] = c.y; wn[4*q+2] = c.z; wn[4*q+3] = c.w;
    }
    #pragma unroll
    for (int j = 0; j < 64; ++j) { KEEP1(wr[j]); KEEP1(wz[j]); KEEP1(wn[j]); }

    const float bhr = bhh[lane], bhz = bhh[64 + lane], bhn = bhh[128 + lane];

    float h = (t0 == 0) ? 0.0f : hN[ch * 128 + dir * 64 + lane];

    const float* gp = Gi + (size_t)dirch * CH * 192;
    // 2-deep prefetch pipeline
    float g0r = gp[lane], g0z = gp[64 + lane], g0n = gp[128 + lane];
    gp += 192;
    float g1r = gp[lane], g1z = gp[64 + lane], g1n = gp[128 + lane];
    gp += 192;

    for (int tl = 0; tl < tlen; ++tl) {
        float g2r = 0.f, g2z = 0.f, g2n = 0.f;
        if (tl + 2 < tlen) { g2r = gp[lane]; g2z = gp[64 + lane]; g2n = gp[128 + lane]; }
        gp += 192;

        float ar0 = 0.f, ar1 = 0.f, az0 = 0.f, az1 = 0.f, an0 = 0.f, an1 = 0.f;
        #pragma unroll
        for (int j = 0; j < 64; j += 2) {
            float hj0 = bcast(h, j);
            float hj1 = bcast(h, j + 1);
            ar0 = fmaf(wr[j],     hj0, ar0);
            az0 = fmaf(wz[j],     hj0, az0);
            an0 = fmaf(wn[j],     hj0, an0);
            ar1 = fmaf(wr[j + 1], hj1, ar1);
            az1 = fmaf(wz[j + 1], hj1, az1);
            an1 = fmaf(wn[j + 1], hj1, an1);
        }
        float r = sigm(g0r + bhr + (ar0 + ar1));
        float z = sigm(g0z + bhz + (az0 + az1));
        float n = tanhfast(g0n + r * ((an0 + an1) + bhn));
        h = (1.0f - z) * n + z * h;

        g0r = g1r; g0z = g1z; g0n = g1n;
        g1r = g2r; g1z = g2z; g1n = g2n;
    }
    hN[ch * 128 + dir * 64 + lane] = h;
}

// ================= K2-fallback: original in-kernel GRU =================
#define CHUNK 100
__global__ __launch_bounds__(64) void k_gru(
    const float* __restrict__ x3,
    const float* __restrict__ wih_f, const float* __restrict__ whh_f,
    const float* __restrict__ bih_f, const float* __restrict__ bhh_f,
    const float* __restrict__ wih_b, const float* __restrict__ whh_b,
    const float* __restrict__ bih_b, const float* __restrict__ bhh_b,
    float* __restrict__ hN)
{
    const int lane = threadIdx.x;
    const int ch   = blockIdx.x;
    const int dir  = blockIdx.y;
    const float* wih = dir ? wih_b : wih_f;
    const float* whh = dir ? whh_b : whh_f;
    const float* bih = dir ? bih_b : bih_f;
    const float* bhh = dir ? bhh_b : bhh_f;

    __shared__ __align__(16) float sh[64];
    __shared__ __align__(16) float sx[CHUNK * 32];

    float4 wir[8], wiz[8], win[8];
    const float4* wih4 = (const float4*)wih;
    #pragma unroll
    for (int k = 0; k < 8; ++k) {
        wir[k] = wih4[(0   + lane) * 8 + k];
        wiz[k] = wih4[(64  + lane) * 8 + k];
        win[k] = wih4[(128 + lane) * 8 + k];
    }
    float4 whr[16], whz[16], whn[16];
    const float4* whh4 = (const float4*)whh;
    #pragma unroll
    for (int j = 0; j < 16; ++j) {
        whr[j] = whh4[(0   + lane) * 16 + j];
        whz[j] = whh4[(64  + lane) * 16 + j];
        whn[j] = whh4[(128 + lane) * 16 + j];
    }
    const float bir = bih[lane], biz = bih[64 + lane], bin_ = bih[128 + lane];
    const float bhr = bhh[lane], bhz = bhh[64 + lane], bhn  = bhh[128 + lane];

    float h = 0.0f;
    sh[lane] = 0.0f;
    __syncthreads();

    const float* xch = x3 + (size_t)ch * L3O * 32;
    for (int c0 = 0; c0 < L3O; c0 += CHUNK) {
        for (int e = lane; e < CHUNK * 32; e += 64) {
            int tt = e >> 5, k = e & 31;
            int sidx = c0 + tt;
            int t = dir ? (L3O - 1 - sidx) : sidx;
            sx[e] = xch[t * 32 + k];
        }
        __syncthreads();
        for (int tl = 0; tl < CHUNK; ++tl) {
            const float4* xv4 = (const float4*)(sx + tl * 32);
            float gr = 0.f, gz = 0.f, gn = 0.f;
            #pragma unroll
            for (int k = 0; k < 8; ++k) {
                float4 x4 = xv4[k];
                gr += dot4(wir[k], x4); gz += dot4(wiz[k], x4); gn += dot4(win[k], x4);
            }
            float hr = 0.f, hz = 0.f, hn = 0.f;
            const float4* sh4 = (const float4*)sh;
            #pragma unroll
            for (int j = 0; j < 16; ++j) {
                float4 h4 = sh4[j];
                hr += dot4(whr[j], h4); hz += dot4(whz[j], h4); hn += dot4(whn[j], h4);
            }
            float r = sigm(gr + bir + hr + bhr);
            float z = sigm(gz + biz + hz + bhz);
            float n = tanhfast(gn + bin_ + r * (hn + bhn));
            h = (1.0f - z) * n + z * h;
            __syncthreads();
            sh[lane] = h;
            __syncthreads();
        }
    }
    hN[ch * 128 + dir * 64 + lane] = h;
}

// ================= K3a: row normalize + hw1 = h_n @ gcn1_w.T =================
__global__ __launch_bounds__(128) void k_norm(
    const float* __restrict__ hN, const float* __restrict__ gcn1_w,
    float* __restrict__ Xn, float* __restrict__ XnT, float* __restrict__ hw1)
{
    const int i = blockIdx.x, tid = threadIdx.x;
    __shared__ float red[128];
    __shared__ float row[128];
    float v = hN[i * 128 + tid];
    row[tid] = v;
    red[tid] = v;
    __syncthreads();
    for (int s = 64; s > 0; s >>= 1) { if (tid < s) red[tid] += red[tid + s]; __syncthreads(); }
    float mean = red[0] / 128.0f;
    __syncthreads();
    float d = v - mean;
    red[tid] = d * d;
    __syncthreads();
    for (int s = 64; s > 0; s >>= 1) { if (tid < s) red[tid] += red[tid + s]; __syncthreads(); }
    float sd = sqrtf(red[0] / 127.0f);
    float xn = d / (sd + 1e-6f);
    Xn[i * 128 + tid] = xn;
    XnT[tid * 256 + i] = xn;
    if (tid < 32) {
        float acc = 0.f;
        for (int k = 0; k < 128; ++k) acc += row[k] * gcn1_w[tid * 128 + k];
        hw1[i * 32 + tid] = acc;
    }
}

// ================= K3b: corr row -> adjacency + degree =================
__global__ __launch_bounds__(256) void k_corr(
    const float* __restrict__ Xn, const float* __restrict__ XnT,
    float* __restrict__ A, float* __restrict__ deg)
{
    const int i = blockIdx.x, tid = threadIdx.x;
    __shared__ float xi[128];
    __shared__ float red[256];
    if (tid < 128) xi[tid] = Xn[i * 128 + tid];
    __syncthreads();
    float c = 0.f;
    for (int k = 0; k < 128; ++k) c += xi[k] * XnT[k * 256 + tid];
    c *= (1.0f / 128.0f);
    float a = (fabsf(c) > 0.7f) ? 1.0f : 0.0f;
    A[i * 256 + tid] = a;
    red[tid] = a;
    __syncthreads();
    for (int s = 128; s > 0; s >>= 1) { if (tid < s) red[tid] += red[tid + s]; __syncthreads(); }
    if (tid == 0) deg[i] = red[0];
}

// ================= K3c/d: GCN layer (+ optional next-layer feature GEMM) =====
__global__ __launch_bounds__(256) void k_gcn(
    const float* __restrict__ A, const float* __restrict__ deg,
    const float* __restrict__ hw, const float* __restrict__ bias,
    const float* __restrict__ wNext,
    float* __restrict__ hOut, float* __restrict__ hwNext)
{
    const int i = blockIdx.x, tid = threadIdx.x;
    const int f = tid & 31, grp = tid >> 5;
    __shared__ float aj[256];
    __shared__ float red[8][32];
    __shared__ float hrow[32];
    float dj = rsqrtf(fmaxf(deg[tid], 1e-12f));
    aj[tid] = A[i * 256 + tid] * dj;
    __syncthreads();
    float p = 0.f;
    for (int j = grp * 32; j < grp * 32 + 32; ++j) p += aj[j] * hw[j * 32 + f];
    red[grp][f] = p;
    __syncthreads();
    if (grp == 0) {
        float s = 0.f;
        #pragma unroll
        for (int g = 0; g < 8; ++g) s += red[g][f];
        float di = rsqrtf(fmaxf(deg[i], 1e-12f));
        float o = fmaxf(bias[f] + di * s, 0.0f);
        hOut[i * 32 + f] = o;
        hrow[f] = o;
    }
    __syncthreads();
    if (wNext != nullptr && grp == 0) {
        float acc = 0.f;
        #pragma unroll
        for (int k = 0; k < 32; ++k) acc += hrow[k] * wNext[f * 32 + k];
        hwNext[i * 32 + f] = acc;
    }
}

// ================= K3e: mean + classifier =================
__global__ __launch_bounds__(64) void k_head(
    const float* __restrict__ h2, const float* __restrict__ cls_w,
    const float* __restrict__ cls_b, float* __restrict__ out)
{
    const int tid = threadIdx.x;
    __shared__ float mean[32];
    if (tid < 32) {
        float s = 0.f;
        for (int i = 0; i < 256; ++i) s += h2[i * 32 + tid];
        mean[tid] = s * (1.0f / 256.0f);
    }
    __syncthreads();
    if (tid < 2) {
        float s = cls_b[tid];
        #pragma unroll
        for (int fe = 0; fe < 32; ++fe) s += mean[fe] * cls_w[tid * 32 + fe];
        out[tid] = s;
    }
}

extern "C" void kernel_launch(void* const* d_in, const int* in_sizes, int n_in,
                              void* d_out, int out_size, void* d_ws, size_t ws_size,
                              hipStream_t stream) {
    const float* data    = (const float*)d_in[0];
    const float* conv1_w = (const float*)d_in[1];
    const float* conv1_b = (const float*)d_in[2];
    const float* conv2_w = (const float*)d_in[3];
    const float* conv2_b = (const float*)d_in[4];
    const float* conv3_w = (const float*)d_in[5];
    const float* conv3_b = (const float*)d_in[6];
    const float* wih_f   = (const float*)d_in[7];
    const float* whh_f   = (const float*)d_in[8];
    const float* bih_f   = (const float*)d_in[9];
    const float* bhh_f   = (const float*)d_in[10];
    const float* wih_b   = (const float*)d_in[11];
    const float* whh_b   = (const float*)d_in[12];
    const float* bih_b   = (const float*)d_in[13];
    const float* bhh_b   = (const float*)d_in[14];
    const float* gcn1_w  = (const float*)d_in[15];
    const float* gcn1_b  = (const float*)d_in[16];
    const float* gcn2_w  = (const float*)d_in[17];
    const float* gcn2_b  = (const float*)d_in[18];
    const float* cls_w   = (const float*)d_in[19];
    const float* cls_b   = (const float*)d_in[20];

    float* ws  = (float*)d_ws;
    float* x3  = ws;                   // 256*800*32 = 6,553,600
    float* hN  = x3 + 6553600;         // 256*128
    float* Xn  = hN + 32768;           // 256*128
    float* XnT = Xn + 32768;           // 128*256
    float* A   = XnT + 32768;          // 256*256
    float* deg = A + 65536;            // 256
    float* hw1 = deg + 256;            // 256*32
    float* h1  = hw1 + 8192;           // 256*32
    float* hw2 = h1 + 8192;            // 256*32
    float* h2  = hw2 + 8192;           // 256*32
    float* Gi  = h2 + 8192;            // 512*CH*192 (variable)

    const size_t BASE = 6726272;       // floats used before Gi
    const size_t avail = ws_size / 4;
    int CH = 0;
    if      (avail >= BASE + (size_t)512 * 800 * 192) CH = 800;
    else if (avail >= BASE + (size_t)512 * 100 * 192) CH = 100;
    else if (avail >= BASE + (size_t)512 *  50 * 192) CH = 50;
    else if (avail >= BASE + (size_t)512 *  25 * 192) CH = 25;

    k_conv<<<dim3(32, 256), 256, 0, stream>>>(data, conv1_w, conv1_b, conv2_w, conv2_b,
                                              conv3_w, conv3_b, x3);
    if (CH) {
        for (int c0 = 0; c0 < L3O; c0 += CH) {
            k_gi<<<dim3(512, CH / 25), 192, 0, stream>>>(x3, wih_f, bih_f, wih_b, bih_b,
                                                         Gi, c0, CH);
            k_gru3<<<dim3(256, 2), 64, 0, stream>>>(Gi, whh_f, bhh_f, whh_b, bhh_b,
                                                    hN, c0, CH, CH);
        }
    } else {
        k_gru<<<dim3(256, 2), 64, 0, stream>>>(x3, wih_f, whh_f, bih_f, bhh_f,
                                               wih_b, whh_b, bih_b, bhh_b, hN);
    }
    k_norm<<<256, 128, 0, stream>>>(hN, gcn1_w, Xn, XnT, hw1);
    k_corr<<<256, 256, 0, stream>>>(Xn, XnT, A, deg);
    k_gcn<<<256, 256, 0, stream>>>(A, deg, hw1, gcn1_b, gcn2_w, h1, hw2);
    k_gcn<<<256, 256, 0, stream>>>(A, deg, hw2, gcn2_b, nullptr, h2, nullptr);
    k_head<<<1, 64, 0, stream>>>(h2, cls_w, cls_b, (float*)d_out);
}